// Round 2
// baseline (185.455 us; speedup 1.0000x reference)
//
#include <hip/hip_runtime.h>
#include <stdint.h>

#define H 8
#define DMODEL 1024
#define DCON 768
#define DPOS 256
#define TT 8192

typedef unsigned short u16;
typedef __attribute__((ext_vector_type(8))) short bf16x8;
typedef __attribute__((ext_vector_type(4))) short bf16x4;
typedef __attribute__((ext_vector_type(4))) float f32x4;

typedef __attribute__((address_space(1))) const void as1_void;
typedef __attribute__((address_space(3))) void as3_void;

__device__ __forceinline__ void async_copy16(const void* g, void* l) {
  __builtin_amdgcn_global_load_lds((as1_void*)g, (as3_void*)l, 16, 0, 0);
}

__device__ __forceinline__ short f2bf(float x) {
  unsigned u = __builtin_bit_cast(unsigned, x);
  u = (u + 0x7fffu + ((u >> 16) & 1u)) >> 16;
  return (short)u;
}

// ---------------- small prep kernels ----------------

__global__ __launch_bounds__(256) void cvt_x(const float* __restrict__ in, u16* __restrict__ X) {
  size_t i = (size_t)blockIdx.x * 256 + threadIdx.x;   // one float4 per thread
  const float4 v = *(const float4*)(in + i * 4);
  bf16x4 o;
  o[0] = f2bf(v.x); o[1] = f2bf(v.y); o[2] = f2bf(v.z); o[3] = f2bf(v.w);
  *(bf16x4*)(X + i * 4) = o;
}

// pack [q|k|v] head-interleaved, TRANSPOSED: Wt[n*K + r], n = h*192 + op*64 + d
__global__ __launch_bounds__(256) void pack_w(const float* __restrict__ wq, const float* __restrict__ wk,
                                              const float* __restrict__ wv, u16* __restrict__ Wt, int K) {
  int idx = blockIdx.x * 256 + threadIdx.x;
  int n = idx / K, r = idx % K;
  int h = n / 192, rem = n % 192, op = rem >> 6, d = rem & 63;
  const float* src = (op == 0) ? wq : (op == 1) ? wk : wv;
  Wt[idx] = (u16)f2bf(src[((size_t)h * K + r) * 64 + d]);
}

// transpose proj weight: w (512, Ncols) -> Wt (Ncols, 512)
__global__ __launch_bounds__(256) void pack_wp(const float* __restrict__ w, u16* __restrict__ Wt, int Ncols) {
  int idx = blockIdx.x * 256 + threadIdx.x;
  int c = idx >> 9, j = idx & 511;
  Wt[idx] = (u16)f2bf(w[(size_t)j * Ncols + c]);
}

// Vg (H*T, 128) -> Vtg (H*B, 128, 1024)
__global__ __launch_bounds__(256) void transpose_v(const u16* __restrict__ Vg, u16* __restrict__ Vtg) {
  int bid = blockIdx.x;
  int dt = bid & 1, lt = (bid >> 1) & 15, hb = bid >> 5;
  __shared__ u16 tile[64][72];
  int tid = threadIdx.x;
  int c8 = (tid & 7) * 8;
#pragma unroll
  for (int p = 0; p < 2; ++p) {
    int r = p * 32 + (tid >> 3);
    bf16x8 v = *(const bf16x8*)(Vg + ((size_t)hb * 1024 + lt * 64 + r) * 128 + dt * 64 + c8);
#pragma unroll
    for (int j = 0; j < 8; ++j) tile[c8 + j][r] = (u16)v[j];
  }
  __syncthreads();
#pragma unroll
  for (int p = 0; p < 2; ++p) {
    int rr = p * 32 + (tid >> 3);
    int cc = (tid & 7) * 8;
    bf16x8 o = *(const bf16x8*)(&tile[rr][cc]);
    *(bf16x8*)(Vtg + ((size_t)hb * 128 + dt * 64 + rr) * 1024 + lt * 64 + cc) = o;
  }
}

// ---------------- NT GEMM (A row-major K-contig, Bt = (N,K) row-major) ----------------
// 128x128 tile, BK=64, 4 waves (2x2 quadrants), 2-phase gload_lds double buffer.
// EPI 0: QKV scatter epilogue. EPI 1: Z = acc + resid (fp32).

template <int EPI>
__global__ __launch_bounds__(256) void gemm_nt(
    const u16* __restrict__ A, int lda, int aoff,
    const u16* __restrict__ Bt, int K,
    u16* __restrict__ q_out, u16* __restrict__ k_out, u16* __restrict__ v_out, int doff,
    const float* __restrict__ resid, float* __restrict__ zout, int coloff) {
  __shared__ char smem[65536];
  auto Asp = [&](int buf) -> char* { return smem + buf * 16384; };
  auto Bsp = [&](int buf) -> char* { return smem + 32768 + buf * 16384; };
  const int tid = threadIdx.x;
  const int lane = tid & 63, wid = tid >> 6;
  const int m0 = blockIdx.x * 128, n0 = blockIdx.y * 128;
  const int KT = K >> 6;

  const int lr = lane >> 3, lcb = (lane & 7) << 4;

  auto stage = [&](int kt, int buf) {
#pragma unroll
    for (int s = 0; s < 4; ++s) {
      int r = wid * 32 + s * 8 + lr;
      int cb = lcb ^ ((r & 7) << 4);
      const char* g = (const char*)(A + (size_t)(m0 + r) * lda + aoff + kt * 64) + cb;
      async_copy16(g, Asp(buf) + (wid * 32 + s * 8) * 128);
    }
#pragma unroll
    for (int s = 0; s < 4; ++s) {
      int r = wid * 32 + s * 8 + lr;
      int cb = lcb ^ ((r & 7) << 4);
      const char* g = (const char*)(Bt + (size_t)(n0 + r) * K + kt * 64) + cb;
      async_copy16(g, Bsp(buf) + (wid * 32 + s * 8) * 128);
    }
  };

  f32x4 acc[4][4];
  const f32x4 fz = {0.f, 0.f, 0.f, 0.f};
#pragma unroll
  for (int i = 0; i < 4; ++i)
#pragma unroll
    for (int j = 0; j < 4; ++j) acc[i][j] = fz;

  const int mwq = (wid >> 1) * 64, nwq = (wid & 1) * 64;
  const int ml = lane & 15, kg = (lane >> 4) << 4;

  auto compute = [&](int buf) {
#pragma unroll
    for (int ks = 0; ks < 2; ++ks) {
      bf16x8 af[4], bfr[4];
#pragma unroll
      for (int f = 0; f < 4; ++f) {
        int rowa = mwq + f * 16 + ml;
        af[f] = *(const bf16x8*)(Asp(buf) + rowa * 128 + ((ks * 64 + kg) ^ ((rowa & 7) << 4)));
        int rowb = nwq + f * 16 + ml;
        bfr[f] = *(const bf16x8*)(Bsp(buf) + rowb * 128 + ((ks * 64 + kg) ^ ((rowb & 7) << 4)));
      }
#pragma unroll
      for (int fm = 0; fm < 4; ++fm)
#pragma unroll
        for (int fn = 0; fn < 4; ++fn)
          acc[fm][fn] = __builtin_amdgcn_mfma_f32_16x16x32_bf16(af[fm], bfr[fn], acc[fm][fn], 0, 0, 0);
    }
  };

  stage(0, 0);
  __syncthreads();
  for (int kt = 0; kt < KT - 1; ++kt) {
    stage(kt + 1, (kt + 1) & 1);
    compute(kt & 1);
    __syncthreads();
  }
  compute((KT - 1) & 1);

  if (EPI == 0) {
#pragma unroll
    for (int fm = 0; fm < 4; ++fm) {
#pragma unroll
      for (int fn = 0; fn < 4; ++fn) {
        int nb = n0 + nwq + fn * 16;
        int h = nb / 192, rem = nb % 192, op = rem >> 6, db = rem & 63;
        u16* dst = (op == 0) ? q_out : (op == 1) ? k_out : v_out;
        int d = doff + db + ml;
#pragma unroll
        for (int r = 0; r < 4; ++r) {
          int t = m0 + mwq + fm * 16 + (lane >> 4) * 4 + r;
          dst[((size_t)h * TT + t) * 128 + d] = (u16)f2bf(acc[fm][fn][r]);
        }
      }
    }
  } else {
#pragma unroll
    for (int fm = 0; fm < 4; ++fm)
#pragma unroll
      for (int fn = 0; fn < 4; ++fn) {
        int col = coloff + n0 + nwq + fn * 16 + ml;
#pragma unroll
        for (int r = 0; r < 4; ++r) {
          int t = m0 + mwq + fm * 16 + (lane >> 4) * 4 + r;
          zout[(size_t)t * DMODEL + col] = acc[fm][fn][r] + resid[(size_t)t * DMODEL + col];
        }
      }
  }
}

// ---------------- flash attention ----------------
// grid: h(8) x b(8) x qtile(16, 64 rows). 4 waves x 16 q-rows. Q in regs.
// S^T = mfma(K, Q) -> lane owns a full P-row (q = lane&15). P repacked via 2KB/wave swizzled LDS.
// K: single 16KB buffer; Vt: 2x16KB double buffer; staged via swizzled-source global_load_lds.

__global__ __launch_bounds__(256) void attn_kernel(
    const u16* __restrict__ Qg, const u16* __restrict__ Kg, const u16* __restrict__ Vtg,
    u16* __restrict__ O1g, u16* __restrict__ O2g) {
  __shared__ char smem[57344];
  char* Ksh = smem;                 // 16KB: 64 x 256B
  auto Vshp = [&](int buf) -> char* { return smem + 16384 + buf * 16384; };  // 16KB each: 128 x 128B
  char* Psh = smem + 49152;         // 8KB: 4 waves x 2KB (16 x 128B)

  const int tid = threadIdx.x, lane = tid & 63, wid = tid >> 6;
  const int bid = blockIdx.x;
  const int qt = bid & 15, b = (bid >> 4) & 7, h = bid >> 7;
  const int ml = lane & 15, kgrp = lane >> 4, kg = kgrp << 4;

  const size_t qkbase = ((size_t)h * TT + b * 1024) * 128;
  const size_t vtbase = (size_t)(h * 8 + b) * 128 * 1024;

  // Q fragments in registers (B-operand layout == contiguous 16B per lane)
  bf16x8 qf[4];
  {
    const char* qp = (const char*)(Qg + qkbase + (size_t)(qt * 64 + wid * 16 + ml) * 128);
#pragma unroll
    for (int kk = 0; kk < 4; ++kk) qf[kk] = *(const bf16x8*)(qp + kk * 64 + kg);
  }

  auto stageK = [&](int kv0) {
    int lr = lane >> 4, lcb = (lane & 15) << 4;
#pragma unroll
    for (int s = 0; s < 4; ++s) {
      int r = wid * 16 + s * 4 + lr;
      int cb = lcb ^ ((r & 7) << 4);
      const char* g = (const char*)(Kg + qkbase + (size_t)(kv0 + r) * 128) + cb;
      async_copy16(g, Ksh + (wid * 16 + s * 4) * 256);
    }
  };
  auto stageV = [&](int kv0, int buf) {
    int lr = lane >> 3, lcb = (lane & 7) << 4;
#pragma unroll
    for (int s = 0; s < 4; ++s) {
      int r = wid * 32 + s * 8 + lr;
      int cb = lcb ^ ((r & 7) << 4);
      const char* g = (const char*)(Vtg + vtbase + (size_t)r * 1024 + kv0) + cb;
      async_copy16(g, Vshp(buf) + (wid * 32 + s * 8) * 128);
    }
  };

  f32x4 oacc[8];
  const f32x4 fz = {0.f, 0.f, 0.f, 0.f};
#pragma unroll
  for (int i = 0; i < 8; ++i) oacc[i] = fz;
  float mrun = -3.0e38f, lrun = 0.f;
  const float C2 = 0.045084219952754514f;  // log2(e)/32

  char* Pw = Psh + wid * 2048;

  stageK(0);
  stageV(0, 0);
  __syncthreads();

  for (int it = 0; it < 16; ++it) {
    // S^T = K @ Q^T  (C: col = q = lane&15, row = kv)
    f32x4 s[4];
#pragma unroll
    for (int i = 0; i < 4; ++i) s[i] = fz;
#pragma unroll
    for (int kk = 0; kk < 4; ++kk) {
#pragma unroll
      for (int rt = 0; rt < 4; ++rt) {
        int row = rt * 16 + ml;
        bf16x8 kf = *(const bf16x8*)(Ksh + row * 256 + ((kk * 64 + kg) ^ ((row & 7) << 4)));
        s[rt] = __builtin_amdgcn_mfma_f32_16x16x32_bf16(kf, qf[kk], s[rt], 0, 0, 0);
      }
    }
    __syncthreads();  // all waves done reading Ksh
    if (it < 15) {
      stageK((it + 1) * 64);
      stageV((it + 1) * 64, (it + 1) & 1);
    }

    // online softmax: each lane holds 16 S values of row q=ml (kv = rt*16 + kgrp*4 + r)
    float tm = -3.0e38f;
#pragma unroll
    for (int rt = 0; rt < 4; ++rt)
#pragma unroll
      for (int r = 0; r < 4; ++r) tm = fmaxf(tm, s[rt][r]);
    tm = fmaxf(tm, __shfl_xor(tm, 16));
    tm = fmaxf(tm, __shfl_xor(tm, 32));
    float mnew = fmaxf(mrun, tm);
    float fsc = exp2f((mrun - mnew) * C2);
    float psum = 0.f;
#pragma unroll
    for (int rt = 0; rt < 4; ++rt) {
      bf16x4 pv;
#pragma unroll
      for (int r = 0; r < 4; ++r) {
        float p = exp2f((s[rt][r] - mnew) * C2);
        psum += p;
        pv[r] = f2bf(p);
      }
      int cb = (rt * 32 + (kgrp << 3)) ^ ((ml & 7) << 4);
      *(bf16x4*)(Pw + ml * 128 + cb) = pv;  // b64 packed write
    }
    psum += __shfl_xor(psum, 16);
    psum += __shfl_xor(psum, 32);
    lrun = lrun * fsc + psum;
    mrun = mnew;

    // rescale O (rows of O are q = kgrp*4 + r)
    float fr[4];
#pragma unroll
    for (int r = 0; r < 4; ++r) fr[r] = __shfl(fsc, kgrp * 4 + r);
#pragma unroll
    for (int vt = 0; vt < 8; ++vt)
#pragma unroll
      for (int r = 0; r < 4; ++r) oacc[vt][r] *= fr[r];

    // P A-fragments back from LDS
    bf16x8 pa[2];
#pragma unroll
    for (int ks = 0; ks < 2; ++ks)
      pa[ks] = *(const bf16x8*)(Pw + ml * 128 + ((ks * 64 + kg) ^ ((ml & 7) << 4)));

    // O += P @ V  (B-frag from transposed V tile)
    int buf = it & 1;
#pragma unroll
    for (int vt = 0; vt < 8; ++vt) {
#pragma unroll
      for (int ks = 0; ks < 2; ++ks) {
        int row = vt * 16 + ml;
        bf16x8 vf = *(const bf16x8*)(Vshp(buf) + row * 128 + ((ks * 64 + kg) ^ ((row & 7) << 4)));
        oacc[vt] = __builtin_amdgcn_mfma_f32_16x16x32_bf16(pa[ks], vf, oacc[vt], 0, 0, 0);
      }
    }
    __syncthreads();  // drains next-tile staging
  }

  // normalize + write split output (T, H*64) x2
  float rl[4];
#pragma unroll
  for (int r = 0; r < 4; ++r) rl[r] = 1.f / __shfl(lrun, kgrp * 4 + r);
#pragma unroll
  for (int vt = 0; vt < 8; ++vt) {
#pragma unroll
    for (int r = 0; r < 4; ++r) {
      int trow = b * 1024 + qt * 64 + wid * 16 + kgrp * 4 + r;
      float ov = oacc[vt][r] * rl[r];
      if (vt < 4)
        O1g[(size_t)trow * 512 + h * 64 + vt * 16 + ml] = (u16)f2bf(ov);
      else
        O2g[(size_t)trow * 512 + h * 64 + (vt - 4) * 16 + ml] = (u16)f2bf(ov);
    }
  }
}

// ---------------- layernorm ----------------
__global__ __launch_bounds__(256) void ln_kernel(const float* __restrict__ Z, const float* __restrict__ ga,
                                                 const float* __restrict__ gb, float* __restrict__ out) {
  int row = blockIdx.x, tid = threadIdx.x;
  const float4 v = *(const float4*)(Z + (size_t)row * 1024 + tid * 4);
  float s = v.x + v.y + v.z + v.w;
  float s2 = v.x * v.x + v.y * v.y + v.z * v.z + v.w * v.w;
#pragma unroll
  for (int d = 1; d < 64; d <<= 1) {
    s += __shfl_xor(s, d);
    s2 += __shfl_xor(s2, d);
  }
  __shared__ float red[8];
  int wid = tid >> 6, lane = tid & 63;
  if (lane == 0) { red[wid] = s; red[4 + wid] = s2; }
  __syncthreads();
  float ts = red[0] + red[1] + red[2] + red[3];
  float ts2 = red[4] + red[5] + red[6] + red[7];
  float mu = ts * (1.f / 1024.f);
  float var = (ts2 - ts * mu) * (1.f / 1023.f);
  float inv = 1.f / (sqrtf(var) + 0.001f);
  const float4 a = *(const float4*)(ga + tid * 4);
  const float4 bb = *(const float4*)(gb + tid * 4);
  float4 o;
  o.x = (v.x - mu) * inv * a.x + bb.x;
  o.y = (v.y - mu) * inv * a.y + bb.y;
  o.z = (v.z - mu) * inv * a.z + bb.z;
  o.w = (v.w - mu) * inv * a.w + bb.w;
  *(float4*)(out + (size_t)row * 1024 + tid * 4) = o;
}

// ---------------- launch ----------------
extern "C" void kernel_launch(void* const* d_in, const int* in_sizes, int n_in,
                              void* d_out, int out_size, void* d_ws, size_t ws_size,
                              hipStream_t stream) {
  (void)in_sizes; (void)n_in; (void)out_size; (void)ws_size;
  const float* inp = (const float*)d_in[0];
  const float* w_qs1 = (const float*)d_in[1];
  const float* w_ks1 = (const float*)d_in[2];
  const float* w_vs1 = (const float*)d_in[3];
  const float* w_qs2 = (const float*)d_in[4];
  const float* w_ks2 = (const float*)d_in[5];
  const float* w_vs2 = (const float*)d_in[6];
  const float* w_proj1 = (const float*)d_in[7];
  const float* w_proj2 = (const float*)d_in[8];
  const float* ln_a = (const float*)d_in[9];
  const float* ln_b = (const float*)d_in[10];
  float* out = (float*)d_out;

  char* ws = (char*)d_ws;
  size_t off = 0;
  auto alloc = [&](size_t bytes) { char* p = ws + off; off += (bytes + 255) & ~(size_t)255; return p; };
  u16* X    = (u16*)alloc((size_t)TT * DMODEL * 2);   // dead after QKV gemms
  u16* Vg   = (u16*)alloc((size_t)H * TT * 128 * 2);  // dead after transpose
  u16* W1t  = (u16*)alloc((size_t)1536 * 768 * 2);
  u16* W2t  = (u16*)alloc((size_t)1536 * 256 * 2);
  u16* Wp1t = (u16*)alloc((size_t)768 * 512 * 2);
  u16* Wp2t = (u16*)alloc((size_t)256 * 512 * 2);
  u16* Qg   = (u16*)alloc((size_t)H * TT * 128 * 2);
  u16* Kg   = (u16*)alloc((size_t)H * TT * 128 * 2);
  u16* Vtg  = (u16*)alloc((size_t)H * TT * 128 * 2);
  u16* O1g  = (u16*)alloc((size_t)TT * 512 * 2);
  u16* O2g  = (u16*)alloc((size_t)TT * 512 * 2);
  float* Z  = (float*)ws;  // aliases X+Vg (both dead by projection time), 32MB

  cvt_x<<<TT * DMODEL / 4 / 256, 256, 0, stream>>>(inp, X);
  pack_w<<<1536 * 768 / 256, 256, 0, stream>>>(w_qs1, w_ks1, w_vs1, W1t, 768);
  pack_w<<<1536 * 256 / 256, 256, 0, stream>>>(w_qs2, w_ks2, w_vs2, W2t, 256);
  pack_wp<<<768 * 512 / 256, 256, 0, stream>>>(w_proj1, Wp1t, 768);
  pack_wp<<<256 * 512 / 256, 256, 0, stream>>>(w_proj2, Wp2t, 256);

  dim3 gq(64, 12);
  gemm_nt<0><<<gq, 256, 0, stream>>>(X, DMODEL, 0, W1t, 768, Qg, Kg, Vg, 0, nullptr, nullptr, 0);
  gemm_nt<0><<<gq, 256, 0, stream>>>(X, DMODEL, 768, W2t, 256, Qg, Kg, Vg, 64, nullptr, nullptr, 0);

  transpose_v<<<2048, 256, 0, stream>>>(Vg, Vtg);
  attn_kernel<<<1024, 256, 0, stream>>>(Qg, Kg, Vtg, O1g, O2g);

  dim3 gp1(64, 6), gp2(64, 2);
  gemm_nt<1><<<gp1, 256, 0, stream>>>(O1g, 512, 0, Wp1t, 512, nullptr, nullptr, nullptr, 0, inp, Z, 0);
  gemm_nt<1><<<gp2, 256, 0, stream>>>(O2g, 512, 0, Wp2t, 512, nullptr, nullptr, nullptr, 0, inp, Z, 768);

  ln_kernel<<<TT, 256, 0, stream>>>(Z, ln_a, ln_b, out);
}

// Round 3
// 157.048 us; speedup vs baseline: 1.1809x; 1.1809x over previous
//
#include <hip/hip_runtime.h>
#include <stdint.h>

#define H 8
#define DMODEL 1024
#define DCON 768
#define DPOS 256
#define TT 8192

typedef unsigned short u16;
typedef __attribute__((ext_vector_type(8))) short bf16x8;
typedef __attribute__((ext_vector_type(4))) short bf16x4;
typedef __attribute__((ext_vector_type(4))) float f32x4;

typedef __attribute__((address_space(1))) const void as1_void;
typedef __attribute__((address_space(3))) void as3_void;

__device__ __forceinline__ void async_copy16(const void* g, void* l) {
  __builtin_amdgcn_global_load_lds((as1_void*)g, (as3_void*)l, 16, 0, 0);
}

__device__ __forceinline__ short f2bf(float x) {
  unsigned u = __builtin_bit_cast(unsigned, x);
  u = (u + 0x7fffu + ((u >> 16) & 1u)) >> 16;
  return (short)u;
}

__device__ __forceinline__ short f2bf_trunc(float x) {
  return (short)(__builtin_bit_cast(unsigned, x) >> 16);
}

// ---------------- small prep kernels ----------------

__global__ __launch_bounds__(256) void cvt_x(const float* __restrict__ in, u16* __restrict__ X) {
  size_t i = (size_t)blockIdx.x * 256 + threadIdx.x;   // one float4 per thread
  const float4 v = *(const float4*)(in + i * 4);
  bf16x4 o;
  o[0] = f2bf(v.x); o[1] = f2bf(v.y); o[2] = f2bf(v.z); o[3] = f2bf(v.w);
  *(bf16x4*)(X + i * 4) = o;
}

// pack [q|k|v] head-interleaved, TRANSPOSED: Wt[n*K + r], n = h*192 + op*64 + d
__global__ __launch_bounds__(256) void pack_w(const float* __restrict__ wq, const float* __restrict__ wk,
                                              const float* __restrict__ wv, u16* __restrict__ Wt, int K) {
  int idx = blockIdx.x * 256 + threadIdx.x;
  int n = idx / K, r = idx % K;
  int h = n / 192, rem = n % 192, op = rem >> 6, d = rem & 63;
  const float* src = (op == 0) ? wq : (op == 1) ? wk : wv;
  Wt[idx] = (u16)f2bf(src[((size_t)h * K + r) * 64 + d]);
}

// transpose proj weight: w (512, Ncols) -> Wt (Ncols, 512)
__global__ __launch_bounds__(256) void pack_wp(const float* __restrict__ w, u16* __restrict__ Wt, int Ncols) {
  int idx = blockIdx.x * 256 + threadIdx.x;
  int c = idx >> 9, j = idx & 511;
  Wt[idx] = (u16)f2bf(w[(size_t)j * Ncols + c]);
}

// Vg (H*T, 128) -> Vtg (H*B, 128, 1024)
__global__ __launch_bounds__(256) void transpose_v(const u16* __restrict__ Vg, u16* __restrict__ Vtg) {
  int bid = blockIdx.x;
  int dt = bid & 1, lt = (bid >> 1) & 15, hb = bid >> 5;
  __shared__ u16 tile[64][72];
  int tid = threadIdx.x;
  int c8 = (tid & 7) * 8;
#pragma unroll
  for (int p = 0; p < 2; ++p) {
    int r = p * 32 + (tid >> 3);
    bf16x8 v = *(const bf16x8*)(Vg + ((size_t)hb * 1024 + lt * 64 + r) * 128 + dt * 64 + c8);
#pragma unroll
    for (int j = 0; j < 8; ++j) tile[c8 + j][r] = (u16)v[j];
  }
  __syncthreads();
#pragma unroll
  for (int p = 0; p < 2; ++p) {
    int rr = p * 32 + (tid >> 3);
    int cc = (tid & 7) * 8;
    bf16x8 o = *(const bf16x8*)(&tile[rr][cc]);
    *(bf16x8*)(Vtg + ((size_t)hb * 128 + dt * 64 + rr) * 1024 + lt * 64 + cc) = o;
  }
}

// ---------------- NT GEMM (A row-major K-contig, Bt = (N,K) row-major) ----------------
// 128x128 tile, BK=64, 4 waves (2x2 quadrants), 2-phase gload_lds double buffer.
// EPI 0: QKV scatter epilogue. EPI 1: Z = acc + resid (fp32).

template <int EPI>
__global__ __launch_bounds__(256) void gemm_nt(
    const u16* __restrict__ A, int lda, int aoff,
    const u16* __restrict__ Bt, int K,
    u16* __restrict__ q_out, u16* __restrict__ k_out, u16* __restrict__ v_out, int doff,
    const float* __restrict__ resid, float* __restrict__ zout, int coloff) {
  __shared__ char smem[65536];
  auto Asp = [&](int buf) -> char* { return smem + buf * 16384; };
  auto Bsp = [&](int buf) -> char* { return smem + 32768 + buf * 16384; };
  const int tid = threadIdx.x;
  const int lane = tid & 63, wid = tid >> 6;
  const int m0 = blockIdx.x * 128, n0 = blockIdx.y * 128;
  const int KT = K >> 6;

  const int lr = lane >> 3, lcb = (lane & 7) << 4;

  auto stage = [&](int kt, int buf) {
#pragma unroll
    for (int s = 0; s < 4; ++s) {
      int r = wid * 32 + s * 8 + lr;
      int cb = lcb ^ ((r & 7) << 4);
      const char* g = (const char*)(A + (size_t)(m0 + r) * lda + aoff + kt * 64) + cb;
      async_copy16(g, Asp(buf) + (wid * 32 + s * 8) * 128);
    }
#pragma unroll
    for (int s = 0; s < 4; ++s) {
      int r = wid * 32 + s * 8 + lr;
      int cb = lcb ^ ((r & 7) << 4);
      const char* g = (const char*)(Bt + (size_t)(n0 + r) * K + kt * 64) + cb;
      async_copy16(g, Bsp(buf) + (wid * 32 + s * 8) * 128);
    }
  };

  f32x4 acc[4][4];
  const f32x4 fz = {0.f, 0.f, 0.f, 0.f};
#pragma unroll
  for (int i = 0; i < 4; ++i)
#pragma unroll
    for (int j = 0; j < 4; ++j) acc[i][j] = fz;

  const int mwq = (wid >> 1) * 64, nwq = (wid & 1) * 64;
  const int ml = lane & 15, kg = (lane >> 4) << 4;

  auto compute = [&](int buf) {
#pragma unroll
    for (int ks = 0; ks < 2; ++ks) {
      bf16x8 af[4], bfr[4];
#pragma unroll
      for (int f = 0; f < 4; ++f) {
        int rowa = mwq + f * 16 + ml;
        af[f] = *(const bf16x8*)(Asp(buf) + rowa * 128 + ((ks * 64 + kg) ^ ((rowa & 7) << 4)));
        int rowb = nwq + f * 16 + ml;
        bfr[f] = *(const bf16x8*)(Bsp(buf) + rowb * 128 + ((ks * 64 + kg) ^ ((rowb & 7) << 4)));
      }
#pragma unroll
      for (int fm = 0; fm < 4; ++fm)
#pragma unroll
        for (int fn = 0; fn < 4; ++fn)
          acc[fm][fn] = __builtin_amdgcn_mfma_f32_16x16x32_bf16(af[fm], bfr[fn], acc[fm][fn], 0, 0, 0);
    }
  };

  stage(0, 0);
  __syncthreads();
  for (int kt = 0; kt < KT - 1; ++kt) {
    stage(kt + 1, (kt + 1) & 1);
    compute(kt & 1);
    __syncthreads();
  }
  compute((KT - 1) & 1);

  if (EPI == 0) {
#pragma unroll
    for (int fm = 0; fm < 4; ++fm) {
#pragma unroll
      for (int fn = 0; fn < 4; ++fn) {
        int nb = n0 + nwq + fn * 16;
        int h = nb / 192, rem = nb % 192, op = rem >> 6, db = rem & 63;
        u16* dst = (op == 0) ? q_out : (op == 1) ? k_out : v_out;
        int d = doff + db + ml;
#pragma unroll
        for (int r = 0; r < 4; ++r) {
          int t = m0 + mwq + fm * 16 + (lane >> 4) * 4 + r;
          dst[((size_t)h * TT + t) * 128 + d] = (u16)f2bf(acc[fm][fn][r]);
        }
      }
    }
  } else {
#pragma unroll
    for (int fm = 0; fm < 4; ++fm)
#pragma unroll
      for (int fn = 0; fn < 4; ++fn) {
        int col = coloff + n0 + nwq + fn * 16 + ml;
#pragma unroll
        for (int r = 0; r < 4; ++r) {
          int t = m0 + mwq + fm * 16 + (lane >> 4) * 4 + r;
          zout[(size_t)t * DMODEL + col] = acc[fm][fn][r] + resid[(size_t)t * DMODEL + col];
        }
      }
  }
}

// ---------------- flash attention ----------------
// grid: 512 = hb(64) x qt(8); bid = qt*64 + hb so bid%8 == hb%8 (XCD-pinned K/V).
// 8 waves x 16 q-rows = 128-row Q tile. Q in regs. Fixed-max softmax (logits bounded,
// any fixed max cancels exactly): no max tracking, no O rescale.
// K and V double-buffered (80KB dynamic LDS) -> ONE barrier per KV tile.

__global__ __launch_bounds__(512, 4) void attn_kernel(
    const u16* __restrict__ Qg, const u16* __restrict__ Kg, const u16* __restrict__ Vtg,
    u16* __restrict__ O1g, u16* __restrict__ O2g) {
  extern __shared__ char smem[];
  // K: 2 x 16KB @ 0,16384 ; V: 2 x 16KB @ 32768,49152 ; P: 8 waves x 2KB @ 65536
  const int tid = threadIdx.x, lane = tid & 63, wid = tid >> 6;
  const int bid = blockIdx.x;
  const int qt = bid >> 6, hb = bid & 63, h = hb >> 3, b = hb & 7;
  const int ml = lane & 15, kgrp = lane >> 4, kg = kgrp << 4;

  const size_t qkbase = ((size_t)h * TT + b * 1024) * 128;
  const char* Kbyte = (const char*)(Kg + qkbase);
  const char* Vbyte = (const char*)(Vtg + (size_t)hb * 128 * 1024);

  // Q fragments in registers (B-operand layout == contiguous 16B per lane)
  bf16x8 qf[4];
  {
    const char* qp = (const char*)(Qg + qkbase + (size_t)(qt * 128 + wid * 16 + ml) * 128);
#pragma unroll
    for (int kk = 0; kk < 4; ++kk) qf[kk] = *(const bf16x8*)(qp + kk * 64 + kg);
  }

  // staging: 4 chunks of 16B per thread per tile (2 K + 2 V), linear LDS dest,
  // pre-swizzled global source (byte ^ ((row&7)<<4) both sides).
  auto stage = [&](int kv0, int buf) {
#pragma unroll
    for (int s = 0; s < 2; ++s) {
      int c = wid * 128 + s * 64 + lane;
      int row = c >> 3, i16 = (c & 7) << 4;
      const char* g = Kbyte + (size_t)(kv0 + row) * 256 + (i16 ^ ((row & 7) << 4));
      async_copy16(g, smem + buf * 16384 + (wid * 128 + s * 64) * 16);
    }
#pragma unroll
    for (int s = 0; s < 2; ++s) {
      int c = wid * 128 + s * 64 + lane;
      int row = c >> 3, i16 = (c & 7) << 4;
      const char* g = Vbyte + (size_t)row * 2048 + kv0 * 2 + (i16 ^ ((row & 7) << 4));
      async_copy16(g, smem + 32768 + buf * 16384 + (wid * 128 + s * 64) * 16);
    }
  };

  f32x4 oacc[8];
  const f32x4 fz = {0.f, 0.f, 0.f, 0.f};
#pragma unroll
  for (int i = 0; i < 8; ++i) oacc[i] = fz;
  float lrun = 0.f;
  const float C2 = 0.045084219952754514f;  // log2(e)/32

  char* Pw = smem + 65536 + wid * 2048;

  stage(0, 0);
  __syncthreads();

  for (int it = 0; it < 16; ++it) {
    const int cur = it & 1;
    if (it < 15) stage((it + 1) * 64, cur ^ 1);  // into other buffers: no LDS hazard

    // S^T = K @ Q^T  (C: col = q = lane&15, row = kv)
    f32x4 s4[4];
#pragma unroll
    for (int i = 0; i < 4; ++i) s4[i] = fz;
    __builtin_amdgcn_s_setprio(1);
#pragma unroll
    for (int kk = 0; kk < 4; ++kk) {
#pragma unroll
      for (int rt = 0; rt < 4; ++rt) {
        int row = rt * 16 + ml;
        bf16x8 kf = *(const bf16x8*)(smem + cur * 16384 + row * 256 + ((kk * 64 + kg) ^ ((row & 7) << 4)));
        s4[rt] = __builtin_amdgcn_mfma_f32_16x16x32_bf16(kf, qf[kk], s4[rt], 0, 0, 0);
      }
    }
    __builtin_amdgcn_s_setprio(0);

    // fixed-max softmax: P = exp2(S * log2e/32), bounded ~[0.5, 2].
    float psum = 0.f;
#pragma unroll
    for (int rt = 0; rt < 4; ++rt) {
      bf16x4 pv;
#pragma unroll
      for (int r = 0; r < 4; ++r) {
        float p = exp2f(s4[rt][r] * C2);
        psum += p;
        pv[r] = f2bf_trunc(p);
      }
      int cb = (rt * 32 + (kgrp << 3)) ^ ((ml & 7) << 4);
      *(bf16x4*)(Pw + ml * 128 + cb) = pv;  // b64 packed write, per-wave buffer
    }
    psum += __shfl_xor(psum, 16);
    psum += __shfl_xor(psum, 32);
    lrun += psum;

    // P A-fragments back from LDS (same-wave, lgkmcnt auto)
    bf16x8 pa[2];
#pragma unroll
    for (int ks = 0; ks < 2; ++ks)
      pa[ks] = *(const bf16x8*)(Pw + ml * 128 + ((ks * 64 + kg) ^ ((ml & 7) << 4)));

    // O += P @ V
    __builtin_amdgcn_s_setprio(1);
#pragma unroll
    for (int vt = 0; vt < 8; ++vt) {
#pragma unroll
      for (int ks = 0; ks < 2; ++ks) {
        int row = vt * 16 + ml;
        bf16x8 vf = *(const bf16x8*)(smem + 32768 + cur * 16384 + row * 128 + ((ks * 64 + kg) ^ ((row & 7) << 4)));
        oacc[vt] = __builtin_amdgcn_mfma_f32_16x16x32_bf16(pa[ks], vf, oacc[vt], 0, 0, 0);
      }
    }
    __builtin_amdgcn_s_setprio(0);
    __syncthreads();  // waves done with cur; prefetch (into cur^1) drained
  }

  // normalize + write split output (T, H*64) x2
  float rl[4];
#pragma unroll
  for (int r = 0; r < 4; ++r) rl[r] = 1.f / __shfl(lrun, kgrp * 4 + r);
#pragma unroll
  for (int vt = 0; vt < 8; ++vt) {
#pragma unroll
    for (int r = 0; r < 4; ++r) {
      int trow = b * 1024 + qt * 128 + wid * 16 + kgrp * 4 + r;
      float ov = oacc[vt][r] * rl[r];
      if (vt < 4)
        O1g[(size_t)trow * 512 + h * 64 + vt * 16 + ml] = (u16)f2bf(ov);
      else
        O2g[(size_t)trow * 512 + h * 64 + (vt - 4) * 16 + ml] = (u16)f2bf(ov);
    }
  }
}

// ---------------- layernorm ----------------
__global__ __launch_bounds__(256) void ln_kernel(const float* __restrict__ Z, const float* __restrict__ ga,
                                                 const float* __restrict__ gb, float* __restrict__ out) {
  int row = blockIdx.x, tid = threadIdx.x;
  const float4 v = *(const float4*)(Z + (size_t)row * 1024 + tid * 4);
  float s = v.x + v.y + v.z + v.w;
  float s2 = v.x * v.x + v.y * v.y + v.z * v.z + v.w * v.w;
#pragma unroll
  for (int d = 1; d < 64; d <<= 1) {
    s += __shfl_xor(s, d);
    s2 += __shfl_xor(s2, d);
  }
  __shared__ float red[8];
  int wid = tid >> 6, lane = tid & 63;
  if (lane == 0) { red[wid] = s; red[4 + wid] = s2; }
  __syncthreads();
  float ts = red[0] + red[1] + red[2] + red[3];
  float ts2 = red[4] + red[5] + red[6] + red[7];
  float mu = ts * (1.f / 1024.f);
  float var = (ts2 - ts * mu) * (1.f / 1023.f);
  float inv = 1.f / (sqrtf(var) + 0.001f);
  const float4 a = *(const float4*)(ga + tid * 4);
  const float4 bb = *(const float4*)(gb + tid * 4);
  float4 o;
  o.x = (v.x - mu) * inv * a.x + bb.x;
  o.y = (v.y - mu) * inv * a.y + bb.y;
  o.z = (v.z - mu) * inv * a.z + bb.z;
  o.w = (v.w - mu) * inv * a.w + bb.w;
  *(float4*)(out + (size_t)row * 1024 + tid * 4) = o;
}

// ---------------- launch ----------------
extern "C" void kernel_launch(void* const* d_in, const int* in_sizes, int n_in,
                              void* d_out, int out_size, void* d_ws, size_t ws_size,
                              hipStream_t stream) {
  (void)in_sizes; (void)n_in; (void)out_size; (void)ws_size;
  const float* inp = (const float*)d_in[0];
  const float* w_qs1 = (const float*)d_in[1];
  const float* w_ks1 = (const float*)d_in[2];
  const float* w_vs1 = (const float*)d_in[3];
  const float* w_qs2 = (const float*)d_in[4];
  const float* w_ks2 = (const float*)d_in[5];
  const float* w_vs2 = (const float*)d_in[6];
  const float* w_proj1 = (const float*)d_in[7];
  const float* w_proj2 = (const float*)d_in[8];
  const float* ln_a = (const float*)d_in[9];
  const float* ln_b = (const float*)d_in[10];
  float* out = (float*)d_out;

  char* ws = (char*)d_ws;
  size_t off = 0;
  auto alloc = [&](size_t bytes) { char* p = ws + off; off += (bytes + 255) & ~(size_t)255; return p; };
  u16* X    = (u16*)alloc((size_t)TT * DMODEL * 2);   // dead after QKV gemms
  u16* Vg   = (u16*)alloc((size_t)H * TT * 128 * 2);  // dead after transpose
  u16* W1t  = (u16*)alloc((size_t)1536 * 768 * 2);
  u16* W2t  = (u16*)alloc((size_t)1536 * 256 * 2);
  u16* Wp1t = (u16*)alloc((size_t)768 * 512 * 2);
  u16* Wp2t = (u16*)alloc((size_t)256 * 512 * 2);
  u16* Qg   = (u16*)alloc((size_t)H * TT * 128 * 2);
  u16* Kg   = (u16*)alloc((size_t)H * TT * 128 * 2);
  u16* Vtg  = (u16*)alloc((size_t)H * TT * 128 * 2);
  u16* O1g  = (u16*)alloc((size_t)TT * 512 * 2);
  u16* O2g  = (u16*)alloc((size_t)TT * 512 * 2);
  float* Z  = (float*)ws;  // aliases X+Vg (both dead by projection time), 32MB

  cvt_x<<<TT * DMODEL / 4 / 256, 256, 0, stream>>>(inp, X);
  pack_w<<<1536 * 768 / 256, 256, 0, stream>>>(w_qs1, w_ks1, w_vs1, W1t, 768);
  pack_w<<<1536 * 256 / 256, 256, 0, stream>>>(w_qs2, w_ks2, w_vs2, W2t, 256);
  pack_wp<<<768 * 512 / 256, 256, 0, stream>>>(w_proj1, Wp1t, 768);
  pack_wp<<<256 * 512 / 256, 256, 0, stream>>>(w_proj2, Wp2t, 256);

  dim3 gq(64, 12);
  gemm_nt<0><<<gq, 256, 0, stream>>>(X, DMODEL, 0, W1t, 768, Qg, Kg, Vg, 0, nullptr, nullptr, 0);
  gemm_nt<0><<<gq, 256, 0, stream>>>(X, DMODEL, 768, W2t, 256, Qg, Kg, Vg, 64, nullptr, nullptr, 0);

  transpose_v<<<2048, 256, 0, stream>>>(Vg, Vtg);
  attn_kernel<<<512, 512, 81920, stream>>>(Qg, Kg, Vtg, O1g, O2g);

  dim3 gp1(64, 6), gp2(64, 2);
  gemm_nt<1><<<gp1, 256, 0, stream>>>(O1g, 512, 0, Wp1t, 512, nullptr, nullptr, nullptr, 0, inp, Z, 0);
  gemm_nt<1><<<gp2, 256, 0, stream>>>(O2g, 512, 0, Wp2t, 512, nullptr, nullptr, nullptr, 0, inp, Z, 768);

  ln_kernel<<<TT, 256, 0, stream>>>(Z, ln_a, ln_b, out);
}